// Round 6
// baseline (207.334 us; speedup 1.0000x reference)
//
#include <hip/hip_runtime.h>
#include <hip/hip_bf16.h>

#define D_MODEL 512
#define BATCH 4
#define SEQ 2048
#define ROWS (BATCH*SEQ)   // 8192

typedef unsigned short u16;
typedef short bf16x8 __attribute__((ext_vector_type(8)));
typedef float f32x4 __attribute__((ext_vector_type(4)));

__device__ __forceinline__ float bf2f(u16 u) {
    union { unsigned int i; float f; } v;
    v.i = ((unsigned int)u) << 16;
    return v.f;
}
__device__ __forceinline__ u16 f2bf(float f) {
    union { float f; unsigned int i; } v;
    v.f = f;
    unsigned int x = v.i;
    unsigned int r = (x >> 16) & 1u;
    x += 0x7fffu + r;           // round-to-nearest-even
    return (u16)(x >> 16);
}

template<int N> __device__ __forceinline__ void waitv() {
    static_assert(N==0 || N==3 || N==4 || N==6, "unsupported vmcnt");
    if constexpr (N == 0) asm volatile("s_waitcnt vmcnt(0)" ::: "memory");
    if constexpr (N == 3) asm volatile("s_waitcnt vmcnt(3)" ::: "memory");
    if constexpr (N == 4) asm volatile("s_waitcnt vmcnt(4)" ::: "memory");
    if constexpr (N == 6) asm volatile("s_waitcnt vmcnt(6)" ::: "memory");
}

// ---------------- split fp32 -> (hi, lo) bf16 ----------------
__global__ __launch_bounds__(256)
void split_f32_kernel(const float* __restrict__ in, u16* __restrict__ h,
                      u16* __restrict__ l, int n) {
    int i = (blockIdx.x * 256 + threadIdx.x) * 4;
    if (i >= n) return;
    float4 v = *(const float4*)(in + i);
    u16 hh[4], ll[4];
    float vv[4] = { v.x, v.y, v.z, v.w };
    #pragma unroll
    for (int j = 0; j < 4; ++j) {
        u16 hi = f2bf(vv[j]);
        hh[j] = hi;
        ll[j] = f2bf(vv[j] - bf2f(hi));
    }
    *(ushort4*)(h + i) = make_ushort4(hh[0], hh[1], hh[2], hh[3]);
    *(ushort4*)(l + i) = make_ushort4(ll[0], ll[1], ll[2], ll[3]);
}

// ---------------- GEMM: C[m,n] = scale * sum_k A[m,k]*B[n,k] + bias[n] ----------------
// Ring-3 LDS pipeline with COUNTED vmcnt (T4): per iter
//   wait vmcnt(CPW) -> s_barrier -> issue stage(t+2) -> compute buf[t%3].
// stage(t+2) overwrites buf[(t-1)%3]: its reads precede this barrier (safe).
// The wait leaves stage(t+1) in flight across the barrier (never drains to 0
// in steady state). XCD-aware block swizzle for L2 locality (T1).
// BM=128, BK=32, 4 waves (2x2); NF = n-frags per wave => BN = 32*NF.
// AT/BT = split parts (1 = bf16-only hi, 2 = hi+lo); ll term always dropped.
template<int NF, int AT, int BT>
__global__ __launch_bounds__(256)
void gemm_bt(const u16* __restrict__ Ah, const u16* __restrict__ Al,
             const u16* __restrict__ Bh, const u16* __restrict__ Bl,
             const float* __restrict__ bias,
             float* __restrict__ outF, u16* __restrict__ outH, u16* __restrict__ outL,
             int K, int lda, int ldb, int ldc,
             long aStride, long bStride, long cStride,
             float scale, int transposeOut)
{
    constexpr int BN     = 32 * NF;
    constexpr int TILE_A = 128 * 32;          // u16 elems per A tile
    constexpr int TILE_B = BN * 32;
    constexpr int ACH    = 8;                 // 1KiB chunks per A tile
    constexpr int BCH    = BN / 16;           // 1KiB chunks per B tile
    constexpr int NCH    = AT*ACH + BT*BCH;   // total chunks (%4==0 for all cfgs)
    constexpr int CPW    = NCH / 4;           // chunks per wave (3/4/6)
    constexpr int BUFSZ  = AT*TILE_A + BT*TILE_B;
    __shared__ u16 lds[3 * BUFSZ];

    const int tid  = threadIdx.x;
    const int lane = tid & 63;
    const int wave = tid >> 6;
    const int wr = wave >> 1, wc = wave & 1;

    // XCD-aware swizzle (grids are all %8==0): contiguous chunk per XCD
    const int gx = gridDim.x, gy = gridDim.y;
    int nwg = gx * gy * gridDim.z;
    int wg  = blockIdx.x + gx * (blockIdx.y + gy * blockIdx.z);
    int id  = (wg & 7) * (nwg >> 3) + (wg >> 3);
    const int bx = id % gx;
    const int by = (id / gx) % gy;
    const int bz = id / (gx * gy);

    const long aBase = (long)bz * aStride + (long)(bx * 128) * lda;
    const long bBase = (long)bz * bStride + (long)(by * BN) * ldb;

    // Precompute this wave's staging chunks: chunk = 16 rows x 32 elems (1 KiB).
    const u16* csrc[CPW];
    unsigned cdst[CPW];
    #pragma unroll
    for (int i = 0; i < CPW; ++i) {
        int c = wave + i * 4;
        const u16* sb; int ld, lofs, row;
        if (c < AT * ACH) {
            int t = c >> 3;               // A part index
            row = (c & 7) * 16;
            sb = (t == 0 ? Ah : Al) + aBase;
            ld = lda; lofs = t * TILE_A;
        } else {
            int cb = c - AT * ACH;
            int t = cb / BCH;
            row = (cb % BCH) * 16;
            sb = (t == 0 ? Bh : Bl) + bBase;
            ld = ldb; lofs = AT * TILE_A + t * TILE_B;
        }
        csrc[i] = sb + (long)(row + (lane >> 2)) * ld + (lane & 3) * 8;
        cdst[i] = lofs + row * 32;
    }

    auto stage = [&](int buf, int k0) {
        #pragma unroll
        for (int i = 0; i < CPW; ++i) {
            __builtin_amdgcn_global_load_lds(
                (const __attribute__((address_space(1))) unsigned int*)(csrc[i] + k0),
                (__attribute__((address_space(3))) unsigned int*)(&lds[buf * BUFSZ + cdst[i]]),
                16, 0, 0);
        }
    };

    f32x4 acc[4][NF] = {};

    const int frow = lane & 15;
    const int kofs = (lane >> 4) * 8;         // k element offset for b128 read

    const int nt = K >> 5;
    stage(0, 0);
    stage(1, 32);

    for (int t = 0; t < nt; ++t) {
        if (t + 1 < nt) waitv<CPW>();         // stage(t) complete, stage(t+1) in flight
        else            waitv<0>();
        __builtin_amdgcn_s_barrier();
        __builtin_amdgcn_sched_barrier(0);
        if (t + 2 < nt) stage((t + 2) % 3, (t + 2) << 5);

        const int bb = (t % 3) * BUFSZ;
        bf16x8 aH[4], aL[4], bH[NF], bL[NF];
        #pragma unroll
        for (int m = 0; m < 4; ++m) {
            int rA = wr*64 + m*16 + frow;
            aH[m] = *(const bf16x8*)&lds[bb + rA*32 + kofs];
            if constexpr (AT == 2)
                aL[m] = *(const bf16x8*)&lds[bb + TILE_A + rA*32 + kofs];
        }
        #pragma unroll
        for (int n = 0; n < NF; ++n) {
            int rB = wc*(NF*16) + n*16 + frow;
            bH[n] = *(const bf16x8*)&lds[bb + AT*TILE_A + rB*32 + kofs];
            if constexpr (BT == 2)
                bL[n] = *(const bf16x8*)&lds[bb + AT*TILE_A + TILE_B + rB*32 + kofs];
        }
        #pragma unroll
        for (int m = 0; m < 4; ++m)
            #pragma unroll
            for (int n = 0; n < NF; ++n) {
                acc[m][n] = __builtin_amdgcn_mfma_f32_16x16x32_bf16(aH[m], bH[n], acc[m][n], 0, 0, 0);
                if constexpr (BT == 2)
                    acc[m][n] = __builtin_amdgcn_mfma_f32_16x16x32_bf16(aH[m], bL[n], acc[m][n], 0, 0, 0);
                if constexpr (AT == 2)
                    acc[m][n] = __builtin_amdgcn_mfma_f32_16x16x32_bf16(aL[m], bH[n], acc[m][n], 0, 0, 0);
            }
    }

    // epilogue: C/D layout col=lane&15, row=(lane>>4)*4+reg  [m89-verified]
    const int rr = (lane >> 4) * 4;
    #pragma unroll
    for (int n = 0; n < NF; ++n) {
        int colL = by*BN + wc*(NF*16) + n*16 + frow;
        float bv_ = bias ? bias[colL] : 0.0f;
        #pragma unroll
        for (int m = 0; m < 4; ++m) {
            #pragma unroll
            for (int j = 0; j < 4; ++j) {
                int rowL = bx*128 + wr*64 + m*16 + rr + j;
                float val = acc[m][n][j] * scale + bv_;
                if (outF) {
                    outF[(long)bz*cStride + (long)rowL*ldc + colL] = val;
                } else if (transposeOut) {
                    // v path: [B][512][2048]; rowL is global (b*2048 + m)
                    int b = rowL >> 11;
                    int mrow = rowL & 2047;
                    long idx = (long)b*1048576 + (long)colL*2048 + mrow;
                    u16 h = f2bf(val);
                    outH[idx] = h;
                    if (outL) outL[idx] = f2bf(val - bf2f(h));
                } else {
                    long idx = (long)bz*cStride + (long)rowL*ldc + colL;
                    u16 h = f2bf(val);
                    outH[idx] = h;
                    if (outL) outL[idx] = f2bf(val - bf2f(h));
                }
            }
        }
    }
}

// ---------------- row softmax over 2048, in-place, bf16 ----------------
__global__ __launch_bounds__(256)
void softmax_kernel(u16* __restrict__ sh)
{
    const long base = (long)blockIdx.x * 2048;
    const int tid = threadIdx.x;
    const int lane = tid & 63, wave = tid >> 6;
    u16* hp = sh + base + tid * 8;
    bf16x8 hv = *(const bf16x8*)hp;
    float s[8];
    #pragma unroll
    for (int j = 0; j < 8; ++j) s[j] = bf2f((u16)hv[j]);

    float mx = s[0];
    #pragma unroll
    for (int j = 1; j < 8; ++j) mx = fmaxf(mx, s[j]);
    #pragma unroll
    for (int off = 32; off >= 1; off >>= 1) mx = fmaxf(mx, __shfl_xor(mx, off));
    __shared__ float red[8];
    if (lane == 0) red[wave] = mx;
    __syncthreads();
    mx = fmaxf(fmaxf(red[0], red[1]), fmaxf(red[2], red[3]));

    float e[8], sum = 0.f;
    #pragma unroll
    for (int j = 0; j < 8; ++j) { e[j] = __expf(s[j] - mx); sum += e[j]; }
    #pragma unroll
    for (int off = 32; off >= 1; off >>= 1) sum += __shfl_xor(sum, off);
    if (lane == 0) red[4 + wave] = sum;
    __syncthreads();
    sum = red[4] + red[5] + red[6] + red[7];
    float inv = 1.0f / sum;

    bf16x8 ho;
    #pragma unroll
    for (int j = 0; j < 8; ++j) ho[j] = (short)f2bf(e[j] * inv);
    *(bf16x8*)hp = ho;
}

extern "C" void kernel_launch(void* const* d_in, const int* in_sizes, int n_in,
                              void* d_out, int out_size, void* d_ws, size_t ws_size,
                              hipStream_t stream)
{
    const float* x  = (const float*)d_in[0];
    const float* Wq = (const float*)d_in[1];
    const float* bq = (const float*)d_in[2];
    const float* Wk = (const float*)d_in[3];
    const float* bk = (const float*)d_in[4];
    const float* Wv = (const float*)d_in[5];
    const float* bv = (const float*)d_in[6];
    const float* Wo = (const float*)d_in[7];
    const float* bo = (const float*)d_in[8];

    char* p = (char*)d_ws;
    auto alloc = [&](size_t bytes) { char* r = p; p += (bytes + 255) & ~(size_t)255; return r; };

    const size_t XE = (size_t)ROWS * D_MODEL;     // 4,194,304
    const size_t WE = (size_t)D_MODEL * D_MODEL;  // 262,144
    const size_t SE = (size_t)BATCH * SEQ * SEQ;  // 16,777,216

    u16* xh  = (u16*)alloc(XE * 2);
    u16* xl  = (u16*)alloc(XE * 2);
    u16* wqh = (u16*)alloc(WE * 2);
    u16* wql = (u16*)alloc(WE * 2);
    u16* wkh = (u16*)alloc(WE * 2);
    u16* wkl = (u16*)alloc(WE * 2);
    u16* wvh = (u16*)alloc(WE * 2);
    u16* wvl = (u16*)alloc(WE * 2);
    u16* woh = (u16*)alloc(WE * 2);
    u16* wol = (u16*)alloc(WE * 2);
    u16* qh  = (u16*)alloc(XE * 2);
    u16* kh  = (u16*)alloc(XE * 2);
    u16* vTh = (u16*)alloc(XE * 2);
    u16* sh  = (u16*)alloc(SE * 2);
    // att (split) aliases x's split buffers — x is dead after the V projection
    u16* ath = xh;
    u16* atl = xl;

    // 1. splits
    split_f32_kernel<<<XE / 1024, 256, 0, stream>>>(x,  xh,  xl,  (int)XE);
    split_f32_kernel<<<WE / 1024, 256, 0, stream>>>(Wq, wqh, wql, (int)WE);
    split_f32_kernel<<<WE / 1024, 256, 0, stream>>>(Wk, wkh, wkl, (int)WE);
    split_f32_kernel<<<WE / 1024, 256, 0, stream>>>(Wv, wvh, wvl, (int)WE);
    split_f32_kernel<<<WE / 1024, 256, 0, stream>>>(Wo, woh, wol, (int)WE);

    // 2. q/k/v projections: split x @ split W (3-term), bf16-only outputs
    gemm_bt<2,2,2><<<dim3(64, 8, 1), 256, 0, stream>>>(xh, xl, wqh, wql, bq,
        nullptr, qh, nullptr, 512, 512, 512, 512, 0, 0, 0, 1.0f, 0);
    gemm_bt<2,2,2><<<dim3(64, 8, 1), 256, 0, stream>>>(xh, xl, wkh, wkl, bk,
        nullptr, kh, nullptr, 512, 512, 512, 512, 0, 0, 0, 1.0f, 0);
    gemm_bt<2,2,2><<<dim3(64, 8, 1), 256, 0, stream>>>(xh, xl, wvh, wvl, bv,
        nullptr, vTh, nullptr, 512, 512, 512, 512, 0, 0, 0, 1.0f, 1);

    // 3. scores = q@k^T * 1/sqrt(512): pure bf16, 1-term
    gemm_bt<4,1,1><<<dim3(16, 16, 4), 256, 0, stream>>>(qh, nullptr, kh, nullptr, nullptr,
        nullptr, sh, nullptr, 512, 512, 512, 2048,
        (long)SEQ * 512, (long)SEQ * 512, (long)SEQ * SEQ,
        0.044194173824159216f, 0);

    // 4. softmax rows (bf16 in/out)
    softmax_kernel<<<ROWS, 256, 0, stream>>>(sh);

    // 5. att = p @ v: pure bf16, 1-term; split output (feeds final 3-term proj)
    gemm_bt<2,1,1><<<dim3(16, 8, 4), 256, 0, stream>>>(sh, nullptr, vTh, nullptr, nullptr,
        nullptr, ath, atl, 2048, 2048, 2048, 512,
        (long)SEQ * SEQ, (long)512 * SEQ, (long)SEQ * 512,
        1.0f, 0);

    // 6. out = att @ Wo^T + bo: split att @ split Wo (3-term), fp32 out
    gemm_bt<2,2,2><<<dim3(64, 8, 1), 256, 0, stream>>>(ath, atl, woh, wol, bo,
        (float*)d_out, nullptr, nullptr, 512, 512, 512, 512,
        0, 0, 0, 1.0f, 0);
}

// Round 7
// 206.238 us; speedup vs baseline: 1.0053x; 1.0053x over previous
//
#include <hip/hip_runtime.h>
#include <hip/hip_bf16.h>

#define D_MODEL 512
#define BATCH 4
#define SEQ 2048
#define ROWS (BATCH*SEQ)   // 8192

typedef unsigned short u16;
typedef short bf16x8 __attribute__((ext_vector_type(8)));
typedef float f32x4 __attribute__((ext_vector_type(4)));

__device__ __forceinline__ float bf2f(u16 u) {
    union { unsigned int i; float f; } v;
    v.i = ((unsigned int)u) << 16;
    return v.f;
}
__device__ __forceinline__ u16 f2bf(float f) {
    union { float f; unsigned int i; } v;
    v.f = f;
    unsigned int x = v.i;
    unsigned int r = (x >> 16) & 1u;
    x += 0x7fffu + r;           // round-to-nearest-even
    return (u16)(x >> 16);
}

// ---------------- fused prep: split x + 4 weights, concat qkv bias ----------------
// blocks [0,4096): x -> xh/xl.  [4096,5120): weights (256 blocks each,
// Wq/Wk/Wv into concatenated whh/whl at offsets 0/WE/2WE; Wo into woh/wol).
// [5120,5126): bqkv concat (f32).
__global__ __launch_bounds__(256)
void prep_kernel(const float* __restrict__ x,
                 const float* __restrict__ Wq, const float* __restrict__ Wk,
                 const float* __restrict__ Wv, const float* __restrict__ Wo,
                 const float* __restrict__ bq, const float* __restrict__ bk,
                 const float* __restrict__ bv,
                 u16* __restrict__ xh, u16* __restrict__ xl,
                 u16* __restrict__ whh, u16* __restrict__ whl,
                 u16* __restrict__ woh, u16* __restrict__ wol,
                 float* __restrict__ bqkv)
{
    const int blk = blockIdx.x;
    const int tid = threadIdx.x;
    const int WE = 262144;
    if (blk >= 5120) {
        int i = (blk - 5120) * 256 + tid;
        if (i < 1536)
            bqkv[i] = (i < 512) ? bq[i] : (i < 1024) ? bk[i - 512] : bv[i - 1024];
        return;
    }
    const float* src; u16 *dh, *dl; int i;
    if (blk < 4096) {
        src = x; dh = xh; dl = xl;
        i = (blk * 256 + tid) * 4;
    } else {
        int w = (blk - 4096) >> 8;
        src = (w == 0) ? Wq : (w == 1) ? Wk : (w == 2) ? Wv : Wo;
        dh  = (w < 3) ? whh + w * WE : woh;
        dl  = (w < 3) ? whl + w * WE : wol;
        i = (((blk - 4096) & 255) * 256 + tid) * 4;
    }
    float4 v = *(const float4*)(src + i);
    float vv[4] = { v.x, v.y, v.z, v.w };
    u16 hh[4], ll[4];
    #pragma unroll
    for (int j = 0; j < 4; ++j) {
        u16 hi = f2bf(vv[j]);
        hh[j] = hi;
        ll[j] = f2bf(vv[j] - bf2f(hi));
    }
    *(ushort4*)(dh + i) = make_ushort4(hh[0], hh[1], hh[2], hh[3]);
    *(ushort4*)(dl + i) = make_ushort4(ll[0], ll[1], ll[2], ll[3]);
}

// ---------------- GEMM: C[m,n] = scale * sum_k A[m,k]*B[n,k] + bias[n] ----------------
// Round-5 proven schedule: double-buffered LDS, prefetch(t+1) issued BEFORE
// compute(t), single __syncthreads per K-step. Plus XCD-aware block swizzle.
// BM=128, BK=32, 4 waves (2x2); NF = n-frags per wave => BN = 32*NF.
// AT/BT = split parts (1 = bf16-only hi, 2 = hi+lo); ll term always dropped.
// mode: 0 = fp32 outF; 1 = split outH(+outL) row-major; 3 = QKV scatter
//       (cols 0-511 -> outQ, 512-1023 -> outK, 1024-1535 -> outV transposed).
template<int NF, int AT, int BT>
__global__ __launch_bounds__(256)
void gemm_bt(const u16* __restrict__ Ah, const u16* __restrict__ Al,
             const u16* __restrict__ Bh, const u16* __restrict__ Bl,
             const float* __restrict__ bias,
             float* __restrict__ outF, u16* __restrict__ outH, u16* __restrict__ outL,
             u16* __restrict__ outQ, u16* __restrict__ outK, u16* __restrict__ outV,
             int K, int lda, int ldb, int ldc,
             long aStride, long bStride, long cStride,
             float scale, int mode)
{
    constexpr int BN     = 32 * NF;
    constexpr int TILE_A = 128 * 32;          // u16 elems per A tile
    constexpr int TILE_B = BN * 32;
    constexpr int ACH    = 8;                 // 1KiB chunks per A tile
    constexpr int BCH    = BN / 16;           // 1KiB chunks per B tile
    constexpr int NCH    = AT*ACH + BT*BCH;   // total chunks (%4==0 for all cfgs)
    constexpr int CPW    = NCH / 4;           // chunks per wave
    constexpr int BUFSZ  = AT*TILE_A + BT*TILE_B;
    __shared__ u16 lds[2 * BUFSZ];

    const int tid  = threadIdx.x;
    const int lane = tid & 63;
    const int wave = tid >> 6;
    const int wr = wave >> 1, wc = wave & 1;

    // XCD-aware swizzle (all grids %8==0): contiguous chunk per XCD
    const int gx = gridDim.x, gy = gridDim.y;
    int nwg = gx * gy * gridDim.z;
    int wg  = blockIdx.x + gx * (blockIdx.y + gy * blockIdx.z);
    int id  = (wg & 7) * (nwg >> 3) + (wg >> 3);
    const int bx = id % gx;
    const int by = (id / gx) % gy;
    const int bz = id / (gx * gy);

    const long aBase = (long)bz * aStride + (long)(bx * 128) * lda;
    const long bBase = (long)bz * bStride + (long)(by * BN) * ldb;

    // Precompute this wave's staging chunks: chunk = 16 rows x 32 elems (1 KiB).
    const u16* csrc[CPW];
    unsigned cdst[CPW];
    #pragma unroll
    for (int i = 0; i < CPW; ++i) {
        int c = wave + i * 4;
        const u16* sb; int ld, lofs, row;
        if (c < AT * ACH) {
            int t = c >> 3;               // A part index
            row = (c & 7) * 16;
            sb = (t == 0 ? Ah : Al) + aBase;
            ld = lda; lofs = t * TILE_A;
        } else {
            int cb = c - AT * ACH;
            int t = cb / BCH;
            row = (cb % BCH) * 16;
            sb = (t == 0 ? Bh : Bl) + bBase;
            ld = ldb; lofs = AT * TILE_A + t * TILE_B;
        }
        csrc[i] = sb + (long)(row + (lane >> 2)) * ld + (lane & 3) * 8;
        cdst[i] = lofs + row * 32;
    }

    auto stage = [&](int buf, int k0) {
        #pragma unroll
        for (int i = 0; i < CPW; ++i) {
            __builtin_amdgcn_global_load_lds(
                (const __attribute__((address_space(1))) unsigned int*)(csrc[i] + k0),
                (__attribute__((address_space(3))) unsigned int*)(&lds[buf * BUFSZ + cdst[i]]),
                16, 0, 0);
        }
    };

    f32x4 acc[4][NF] = {};

    const int frow = lane & 15;
    const int kofs = (lane >> 4) * 8;         // k element offset for b128 read

    const int nt = K >> 5;
    stage(0, 0);
    __syncthreads();                          // buf0 ready

    int cur = 0;
    for (int t = 0; t < nt; ++t) {
        if (t + 1 < nt) stage(cur ^ 1, (t + 1) << 5);   // async prefetch

        const int bb = cur * BUFSZ;
        bf16x8 aH[4], aL[4], bH[NF], bL[NF];
        #pragma unroll
        for (int m = 0; m < 4; ++m) {
            int rA = wr*64 + m*16 + frow;
            aH[m] = *(const bf16x8*)&lds[bb + rA*32 + kofs];
            if constexpr (AT == 2)
                aL[m] = *(const bf16x8*)&lds[bb + TILE_A + rA*32 + kofs];
        }
        #pragma unroll
        for (int n = 0; n < NF; ++n) {
            int rB = wc*(NF*16) + n*16 + frow;
            bH[n] = *(const bf16x8*)&lds[bb + AT*TILE_A + rB*32 + kofs];
            if constexpr (BT == 2)
                bL[n] = *(const bf16x8*)&lds[bb + AT*TILE_A + TILE_B + rB*32 + kofs];
        }
        #pragma unroll
        for (int m = 0; m < 4; ++m)
            #pragma unroll
            for (int n = 0; n < NF; ++n) {
                acc[m][n] = __builtin_amdgcn_mfma_f32_16x16x32_bf16(aH[m], bH[n], acc[m][n], 0, 0, 0);
                if constexpr (BT == 2)
                    acc[m][n] = __builtin_amdgcn_mfma_f32_16x16x32_bf16(aH[m], bL[n], acc[m][n], 0, 0, 0);
                if constexpr (AT == 2)
                    acc[m][n] = __builtin_amdgcn_mfma_f32_16x16x32_bf16(aL[m], bH[n], acc[m][n], 0, 0, 0);
            }

        __syncthreads();   // next buf ready, cur reusable
        cur ^= 1;
    }

    // epilogue: C/D layout col=lane&15, row=(lane>>4)*4+reg  [m89-verified]
    const int rr = (lane >> 4) * 4;
    #pragma unroll
    for (int n = 0; n < NF; ++n) {
        int colL = by*BN + wc*(NF*16) + n*16 + frow;
        float bv_ = bias ? bias[colL] : 0.0f;
        #pragma unroll
        for (int m = 0; m < 4; ++m) {
            #pragma unroll
            for (int j = 0; j < 4; ++j) {
                int rowL = bx*128 + wr*64 + m*16 + rr + j;
                float val = acc[m][n][j] * scale + bv_;
                if (mode == 0) {
                    outF[(long)bz*cStride + (long)rowL*ldc + colL] = val;
                } else if (mode == 1) {
                    long idx = (long)bz*cStride + (long)rowL*ldc + colL;
                    u16 h = f2bf(val);
                    outH[idx] = h;
                    if (outL) outL[idx] = f2bf(val - bf2f(h));
                } else {
                    // QKV scatter: rowL in [0,8192) global, colL in [0,1536)
                    u16 h = f2bf(val);
                    if (colL < 512) {
                        outQ[(long)rowL*512 + colL] = h;
                    } else if (colL < 1024) {
                        outK[(long)rowL*512 + (colL - 512)] = h;
                    } else {
                        int b = rowL >> 11;
                        outV[(long)b*1048576 + (long)(colL - 1024)*2048 + (rowL & 2047)] = h;
                    }
                }
            }
        }
    }
}

// ---------------- row softmax over 2048, in-place, bf16 ----------------
__global__ __launch_bounds__(256)
void softmax_kernel(u16* __restrict__ sh)
{
    const long base = (long)blockIdx.x * 2048;
    const int tid = threadIdx.x;
    const int lane = tid & 63, wave = tid >> 6;
    u16* hp = sh + base + tid * 8;
    bf16x8 hv = *(const bf16x8*)hp;
    float s[8];
    #pragma unroll
    for (int j = 0; j < 8; ++j) s[j] = bf2f((u16)hv[j]);

    float mx = s[0];
    #pragma unroll
    for (int j = 1; j < 8; ++j) mx = fmaxf(mx, s[j]);
    #pragma unroll
    for (int off = 32; off >= 1; off >>= 1) mx = fmaxf(mx, __shfl_xor(mx, off));
    __shared__ float red[8];
    if (lane == 0) red[wave] = mx;
    __syncthreads();
    mx = fmaxf(fmaxf(red[0], red[1]), fmaxf(red[2], red[3]));

    float e[8], sum = 0.f;
    #pragma unroll
    for (int j = 0; j < 8; ++j) { e[j] = __expf(s[j] - mx); sum += e[j]; }
    #pragma unroll
    for (int off = 32; off >= 1; off >>= 1) sum += __shfl_xor(sum, off);
    if (lane == 0) red[4 + wave] = sum;
    __syncthreads();
    sum = red[4] + red[5] + red[6] + red[7];
    float inv = 1.0f / sum;

    bf16x8 ho;
    #pragma unroll
    for (int j = 0; j < 8; ++j) ho[j] = (short)f2bf(e[j] * inv);
    *(bf16x8*)hp = ho;
}

extern "C" void kernel_launch(void* const* d_in, const int* in_sizes, int n_in,
                              void* d_out, int out_size, void* d_ws, size_t ws_size,
                              hipStream_t stream)
{
    const float* x  = (const float*)d_in[0];
    const float* Wq = (const float*)d_in[1];
    const float* bq = (const float*)d_in[2];
    const float* Wk = (const float*)d_in[3];
    const float* bk = (const float*)d_in[4];
    const float* Wv = (const float*)d_in[5];
    const float* bv = (const float*)d_in[6];
    const float* Wo = (const float*)d_in[7];
    const float* bo = (const float*)d_in[8];

    char* p = (char*)d_ws;
    auto alloc = [&](size_t bytes) { char* r = p; p += (bytes + 255) & ~(size_t)255; return r; };

    const size_t XE = (size_t)ROWS * D_MODEL;     // 4,194,304
    const size_t WE = (size_t)D_MODEL * D_MODEL;  // 262,144
    const size_t SE = (size_t)BATCH * SEQ * SEQ;  // 16,777,216

    u16* xh   = (u16*)alloc(XE * 2);
    u16* xl   = (u16*)alloc(XE * 2);
    u16* whh  = (u16*)alloc(3 * WE * 2);   // concat Wq,Wk,Wv (hi)
    u16* whl  = (u16*)alloc(3 * WE * 2);   // concat (lo)
    u16* woh  = (u16*)alloc(WE * 2);
    u16* wol  = (u16*)alloc(WE * 2);
    float* bqkv = (float*)alloc(1536 * 4);
    u16* qh   = (u16*)alloc(XE * 2);
    u16* kh   = (u16*)alloc(XE * 2);
    u16* vTh  = (u16*)alloc(XE * 2);
    u16* sh   = (u16*)alloc(SE * 2);
    // att (split) aliases x's split buffers — x is dead after the QKV projection
    u16* ath = xh;
    u16* atl = xl;

    // 1. fused prep: all splits + bias concat (1 launch)
    prep_kernel<<<5126, 256, 0, stream>>>(x, Wq, Wk, Wv, Wo, bq, bk, bv,
                                          xh, xl, whh, whl, woh, wol, bqkv);

    // 2. fused QKV projection: [8192,512] @ [1536,512]^T + bqkv, scatter epilogue
    gemm_bt<2,2,2><<<dim3(64, 24, 1), 256, 0, stream>>>(xh, xl, whh, whl, bqkv,
        nullptr, nullptr, nullptr, qh, kh, vTh,
        512, 512, 512, 0, 0, 0, 0, 1.0f, 3);

    // 3. scores = q@k^T * 1/sqrt(512): pure bf16, 1-term
    gemm_bt<4,1,1><<<dim3(16, 16, 4), 256, 0, stream>>>(qh, nullptr, kh, nullptr, nullptr,
        nullptr, sh, nullptr, nullptr, nullptr, nullptr,
        512, 512, 512, 2048,
        (long)SEQ * 512, (long)SEQ * 512, (long)SEQ * SEQ,
        0.044194173824159216f, 1);

    // 4. softmax rows (bf16 in/out)
    softmax_kernel<<<ROWS, 256, 0, stream>>>(sh);

    // 5. att = p @ v: pure bf16, 1-term; split output (feeds final 3-term proj)
    gemm_bt<2,1,1><<<dim3(16, 8, 4), 256, 0, stream>>>(sh, nullptr, vTh, nullptr, nullptr,
        nullptr, ath, atl, nullptr, nullptr, nullptr,
        2048, 2048, 2048, 512,
        (long)SEQ * SEQ, (long)512 * SEQ, (long)SEQ * 512,
        1.0f, 1);

    // 6. out = att @ Wo^T + bo: split att @ split Wo (3-term), fp32 out
    gemm_bt<2,2,2><<<dim3(64, 8, 1), 256, 0, stream>>>(ath, atl, woh, wol, bo,
        (float*)d_out, nullptr, nullptr, nullptr, nullptr, nullptr,
        512, 512, 512, 512, 0, 0, 0, 1.0f, 0);
}

// Round 8
// 204.482 us; speedup vs baseline: 1.0140x; 1.0086x over previous
//
#include <hip/hip_runtime.h>
#include <hip/hip_bf16.h>

#define D_MODEL 512
#define BATCH 4
#define SEQ 2048
#define ROWS (BATCH*SEQ)   // 8192

typedef unsigned short u16;
typedef short bf16x8 __attribute__((ext_vector_type(8)));
typedef float f32x4 __attribute__((ext_vector_type(4)));

__device__ __forceinline__ float bf2f(u16 u) {
    union { unsigned int i; float f; } v;
    v.i = ((unsigned int)u) << 16;
    return v.f;
}
__device__ __forceinline__ u16 f2bf(float f) {
    union { float f; unsigned int i; } v;
    v.f = f;
    unsigned int x = v.i;
    unsigned int r = (x >> 16) & 1u;
    x += 0x7fffu + r;           // round-to-nearest-even
    return (u16)(x >> 16);
}

template<int N> __device__ __forceinline__ void waitv() {
    static_assert(N==0 || N==3 || N==4, "unsupported vmcnt");
    if constexpr (N == 0) asm volatile("s_waitcnt vmcnt(0)" ::: "memory");
    if constexpr (N == 3) asm volatile("s_waitcnt vmcnt(3)" ::: "memory");
    if constexpr (N == 4) asm volatile("s_waitcnt vmcnt(4)" ::: "memory");
}

// ---------------- fused prep: split x + 4 weights ----------------
// blocks [0,4096): x -> xh/xl. [4096,5120): weights, 256 blocks each:
// Wq/Wk/Wv into concat whh/whl at offsets 0/WE/2WE; Wo into woh/wol.
__global__ __launch_bounds__(256)
void prep_kernel(const float* __restrict__ x,
                 const float* __restrict__ Wq, const float* __restrict__ Wk,
                 const float* __restrict__ Wv, const float* __restrict__ Wo,
                 u16* __restrict__ xh, u16* __restrict__ xl,
                 u16* __restrict__ whh, u16* __restrict__ whl,
                 u16* __restrict__ woh, u16* __restrict__ wol)
{
    const int blk = blockIdx.x;
    const int tid = threadIdx.x;
    const int WE = 262144;
    const float* src; u16 *dh, *dl; int i;
    if (blk < 4096) {
        src = x; dh = xh; dl = xl;
        i = (blk * 256 + tid) * 4;
    } else {
        int w = (blk - 4096) >> 8;
        src = (w == 0) ? Wq : (w == 1) ? Wk : (w == 2) ? Wv : Wo;
        dh  = (w < 3) ? whh + w * WE : woh;
        dl  = (w < 3) ? whl + w * WE : wol;
        i = (((blk - 4096) & 255) * 256 + tid) * 4;
    }
    float4 v = *(const float4*)(src + i);
    float vv[4] = { v.x, v.y, v.z, v.w };
    u16 hh[4], ll[4];
    #pragma unroll
    for (int j = 0; j < 4; ++j) {
        u16 hi = f2bf(vv[j]);
        hh[j] = hi;
        ll[j] = f2bf(vv[j] - bf2f(hi));
    }
    *(ushort4*)(dh + i) = make_ushort4(hh[0], hh[1], hh[2], hh[3]);
    *(ushort4*)(dl + i) = make_ushort4(ll[0], ll[1], ll[2], ll[3]);
}

// ======== shared GEMM pieces ========
// C[m,n] = scale * sum_k A[m,k]*B[n,k] + bias[n]
// BM=128, BK=32, 4 waves (2x2); NF = n-frags per wave => BN = 32*NF.
// AT/BT = split parts (1 = bf16-only hi, 2 = hi+lo); ll term dropped.
// mode: 0 = fp32 outF; 1 = split outH(+outL) row-major; 2 = bf16 transposed
//       ([B][512][2048] v layout).

#define GEMM_PROLOG                                                            \
    constexpr int BN     = 32 * NF;                                            \
    constexpr int TILE_A = 128 * 32;                                           \
    constexpr int TILE_B = BN * 32;                                            \
    constexpr int ACH    = 8;                                                  \
    constexpr int BCH    = BN / 16;                                            \
    constexpr int NCH    = AT*ACH + BT*BCH;                                    \
    constexpr int CPW    = NCH / 4;                                            \
    constexpr int BUFSZ  = AT*TILE_A + BT*TILE_B;                              \
    const int tid  = threadIdx.x;                                              \
    const int lane = tid & 63;                                                 \
    const int wave = tid >> 6;                                                 \
    const int wr = wave >> 1, wc = wave & 1;                                   \
    /* XCD-aware swizzle (all grids %8==0) */                                  \
    const int gx = gridDim.x, gy = gridDim.y;                                  \
    int nwg = gx * gy * gridDim.z;                                             \
    int wg  = blockIdx.x + gx * (blockIdx.y + gy * blockIdx.z);                \
    int id  = (wg & 7) * (nwg >> 3) + (wg >> 3);                               \
    const int bx = id % gx;                                                    \
    const int by = (id / gx) % gy;                                             \
    const int bz = id / (gx * gy);                                             \
    const long aBase = (long)bz * aStride + (long)(bx * 128) * lda;            \
    const long bBase = (long)bz * bStride + (long)(by * BN) * ldb;             \
    const u16* csrc[CPW];                                                      \
    unsigned cdst[CPW];                                                        \
    _Pragma("unroll")                                                          \
    for (int i = 0; i < CPW; ++i) {                                            \
        int c = wave + i * 4;                                                  \
        const u16* sb; int ld, lofs, row;                                      \
        if (c < AT * ACH) {                                                    \
            int t = c >> 3;                                                    \
            row = (c & 7) * 16;                                                \
            sb = (t == 0 ? Ah : Al) + aBase;                                   \
            ld = lda; lofs = t * TILE_A;                                       \
        } else {                                                               \
            int cb = c - AT * ACH;                                             \
            int t = cb / BCH;                                                  \
            row = (cb % BCH) * 16;                                             \
            sb = (t == 0 ? Bh : Bl) + bBase;                                   \
            ld = ldb; lofs = AT * TILE_A + t * TILE_B;                         \
        }                                                                      \
        csrc[i] = sb + (long)(row + (lane >> 2)) * ld + (lane & 3) * 8;        \
        cdst[i] = lofs + row * 32;                                             \
    }                                                                          \
    f32x4 acc[4][NF] = {};                                                     \
    const int frow = lane & 15;                                                \
    const int kofs = (lane >> 4) * 8;

#define GEMM_COMPUTE(bb_)                                                      \
    {                                                                          \
        const int bb = (bb_);                                                  \
        bf16x8 aH[4], aL[4], bH[NF], bL[NF];                                   \
        _Pragma("unroll")                                                      \
        for (int m = 0; m < 4; ++m) {                                          \
            int rA = wr*64 + m*16 + frow;                                      \
            aH[m] = *(const bf16x8*)&lds[bb + rA*32 + kofs];                   \
            if constexpr (AT == 2)                                             \
                aL[m] = *(const bf16x8*)&lds[bb + TILE_A + rA*32 + kofs];      \
        }                                                                      \
        _Pragma("unroll")                                                      \
        for (int n = 0; n < NF; ++n) {                                         \
            int rB = wc*(NF*16) + n*16 + frow;                                 \
            bH[n] = *(const bf16x8*)&lds[bb + AT*TILE_A + rB*32 + kofs];       \
            if constexpr (BT == 2)                                             \
                bL[n] = *(const bf16x8*)&lds[bb + AT*TILE_A + TILE_B + rB*32 + kofs]; \
        }                                                                      \
        _Pragma("unroll")                                                      \
        for (int m = 0; m < 4; ++m)                                            \
            _Pragma("unroll")                                                  \
            for (int n = 0; n < NF; ++n) {                                     \
                acc[m][n] = __builtin_amdgcn_mfma_f32_16x16x32_bf16(aH[m], bH[n], acc[m][n], 0, 0, 0); \
                if constexpr (BT == 2)                                         \
                    acc[m][n] = __builtin_amdgcn_mfma_f32_16x16x32_bf16(aH[m], bL[n], acc[m][n], 0, 0, 0); \
                if constexpr (AT == 2)                                         \
                    acc[m][n] = __builtin_amdgcn_mfma_f32_16x16x32_bf16(aL[m], bH[n], acc[m][n], 0, 0, 0); \
            }                                                                  \
    }

#define GEMM_EPILOG                                                            \
    const int rr = (lane >> 4) * 4;                                            \
    _Pragma("unroll")                                                          \
    for (int n = 0; n < NF; ++n) {                                             \
        int colL = by*BN + wc*(NF*16) + n*16 + frow;                           \
        float bv_ = bias ? bias[colL] : 0.0f;                                  \
        _Pragma("unroll")                                                      \
        for (int m = 0; m < 4; ++m) {                                          \
            _Pragma("unroll")                                                  \
            for (int j = 0; j < 4; ++j) {                                      \
                int rowL = bx*128 + wr*64 + m*16 + rr + j;                     \
                float val = acc[m][n][j] * scale + bv_;                        \
                if (mode == 0) {                                               \
                    outF[(long)bz*cStride + (long)rowL*ldc + colL] = val;      \
                } else if (mode == 1) {                                        \
                    long idx = (long)bz*cStride + (long)rowL*ldc + colL;       \
                    u16 h = f2bf(val);                                         \
                    outH[idx] = h;                                             \
                    if (outL) outL[idx] = f2bf(val - bf2f(h));                 \
                } else {                                                       \
                    int b = rowL >> 11;                                        \
                    outH[(long)b*1048576 + (long)colL*2048 + (rowL & 2047)] = f2bf(val); \
                }                                                              \
            }                                                                  \
        }                                                                      \
    }

// ---- 2-buffer variant (round-5 proven; for LDS-fat 2,2,2 configs) ----
template<int NF, int AT, int BT>
__global__ __launch_bounds__(256)
void gemm2(const u16* __restrict__ Ah, const u16* __restrict__ Al,
           const u16* __restrict__ Bh, const u16* __restrict__ Bl,
           const float* __restrict__ bias,
           float* __restrict__ outF, u16* __restrict__ outH, u16* __restrict__ outL,
           int K, int lda, int ldb, int ldc,
           long aStride, long bStride, long cStride,
           float scale, int mode)
{
    GEMM_PROLOG
    __shared__ u16 lds[2 * BUFSZ];
    auto stage = [&](int buf, int k0) {
        #pragma unroll
        for (int i = 0; i < CPW; ++i)
            __builtin_amdgcn_global_load_lds(
                (const __attribute__((address_space(1))) unsigned int*)(csrc[i] + k0),
                (__attribute__((address_space(3))) unsigned int*)(&lds[buf * BUFSZ + cdst[i]]),
                16, 0, 0);
    };
    const int nt = K >> 5;
    stage(0, 0);
    __syncthreads();
    int cur = 0;
    for (int t = 0; t < nt; ++t) {
        if (t + 1 < nt) stage(cur ^ 1, (t + 1) << 5);
        GEMM_COMPUTE(cur * BUFSZ)
        __syncthreads();
        cur ^= 1;
    }
    GEMM_EPILOG
}

// ---- ring-3 counted-vmcnt variant (round-6 proven; for LDS-thin 1-term) ----
template<int NF, int AT, int BT>
__global__ __launch_bounds__(256)
void gemm3(const u16* __restrict__ Ah, const u16* __restrict__ Al,
           const u16* __restrict__ Bh, const u16* __restrict__ Bl,
           const float* __restrict__ bias,
           float* __restrict__ outF, u16* __restrict__ outH, u16* __restrict__ outL,
           int K, int lda, int ldb, int ldc,
           long aStride, long bStride, long cStride,
           float scale, int mode)
{
    GEMM_PROLOG
    __shared__ u16 lds[3 * BUFSZ];
    auto stage = [&](int buf, int k0) {
        #pragma unroll
        for (int i = 0; i < CPW; ++i)
            __builtin_amdgcn_global_load_lds(
                (const __attribute__((address_space(1))) unsigned int*)(csrc[i] + k0),
                (__attribute__((address_space(3))) unsigned int*)(&lds[buf * BUFSZ + cdst[i]]),
                16, 0, 0);
    };
    const int nt = K >> 5;
    stage(0, 0);
    stage(1, 32);
    for (int t = 0; t < nt; ++t) {
        if (t + 1 < nt) waitv<CPW>();   // stage(t) done, stage(t+1) stays in flight
        else            waitv<0>();
        __builtin_amdgcn_s_barrier();
        __builtin_amdgcn_sched_barrier(0);
        if (t + 2 < nt) stage((t + 2) % 3, (t + 2) << 5);
        GEMM_COMPUTE((t % 3) * BUFSZ)
    }
    GEMM_EPILOG
}

// ---------------- row softmax over 2048, in-place, bf16 ----------------
__global__ __launch_bounds__(256)
void softmax_kernel(u16* __restrict__ sh)
{
    const long base = (long)blockIdx.x * 2048;
    const int tid = threadIdx.x;
    const int lane = tid & 63, wave = tid >> 6;
    u16* hp = sh + base + tid * 8;
    bf16x8 hv = *(const bf16x8*)hp;
    float s[8];
    #pragma unroll
    for (int j = 0; j < 8; ++j) s[j] = bf2f((u16)hv[j]);

    float mx = s[0];
    #pragma unroll
    for (int j = 1; j < 8; ++j) mx = fmaxf(mx, s[j]);
    #pragma unroll
    for (int off = 32; off >= 1; off >>= 1) mx = fmaxf(mx, __shfl_xor(mx, off));
    __shared__ float red[8];
    if (lane == 0) red[wave] = mx;
    __syncthreads();
    mx = fmaxf(fmaxf(red[0], red[1]), fmaxf(red[2], red[3]));

    float e[8], sum = 0.f;
    #pragma unroll
    for (int j = 0; j < 8; ++j) { e[j] = __expf(s[j] - mx); sum += e[j]; }
    #pragma unroll
    for (int off = 32; off >= 1; off >>= 1) sum += __shfl_xor(sum, off);
    if (lane == 0) red[4 + wave] = sum;
    __syncthreads();
    sum = red[4] + red[5] + red[6] + red[7];
    float inv = 1.0f / sum;

    bf16x8 ho;
    #pragma unroll
    for (int j = 0; j < 8; ++j) ho[j] = (short)f2bf(e[j] * inv);
    *(bf16x8*)hp = ho;
}

extern "C" void kernel_launch(void* const* d_in, const int* in_sizes, int n_in,
                              void* d_out, int out_size, void* d_ws, size_t ws_size,
                              hipStream_t stream)
{
    const float* x  = (const float*)d_in[0];
    const float* Wq = (const float*)d_in[1];
    const float* bq = (const float*)d_in[2];
    const float* Wk = (const float*)d_in[3];
    const float* bk = (const float*)d_in[4];
    const float* Wv = (const float*)d_in[5];
    const float* bv = (const float*)d_in[6];
    const float* Wo = (const float*)d_in[7];
    const float* bo = (const float*)d_in[8];

    char* p = (char*)d_ws;
    auto alloc = [&](size_t bytes) { char* r = p; p += (bytes + 255) & ~(size_t)255; return r; };

    const size_t XE = (size_t)ROWS * D_MODEL;     // 4,194,304
    const size_t WE = (size_t)D_MODEL * D_MODEL;  // 262,144
    const size_t SE = (size_t)BATCH * SEQ * SEQ;  // 16,777,216

    u16* xh   = (u16*)alloc(XE * 2);
    u16* xl   = (u16*)alloc(XE * 2);
    u16* whh  = (u16*)alloc(3 * WE * 2);   // concat Wq,Wk,Wv (hi)
    u16* whl  = (u16*)alloc(3 * WE * 2);   // concat (lo)
    u16* woh  = (u16*)alloc(WE * 2);
    u16* wol  = (u16*)alloc(WE * 2);
    u16* qh   = (u16*)alloc(XE * 2);
    u16* kh   = (u16*)alloc(XE * 2);
    u16* vTh  = (u16*)alloc(XE * 2);
    u16* sh   = (u16*)alloc(SE * 2);
    // att (split) aliases x's split buffers — x dead after V projection
    u16* ath = xh;
    u16* atl = xl;

    // 1. fused prep (1 launch)
    prep_kernel<<<5120, 256, 0, stream>>>(x, Wq, Wk, Wv, Wo,
                                          xh, xl, whh, whl, woh, wol);

    // 2. q/k/v projections: 3-term split, 2-buffer schedule
    gemm2<2,2,2><<<dim3(64, 8, 1), 256, 0, stream>>>(xh, xl, whh, whl, bq,
        nullptr, qh, nullptr, 512, 512, 512, 512, 0, 0, 0, 1.0f, 1);
    gemm2<2,2,2><<<dim3(64, 8, 1), 256, 0, stream>>>(xh, xl, whh + WE, whl + WE, bk,
        nullptr, kh, nullptr, 512, 512, 512, 512, 0, 0, 0, 1.0f, 1);
    gemm2<2,2,2><<<dim3(64, 8, 1), 256, 0, stream>>>(xh, xl, whh + 2*WE, whl + 2*WE, bv,
        nullptr, vTh, nullptr, 512, 512, 512, 512, 0, 0, 0, 1.0f, 2);

    // 3. scores = q@k^T * 1/sqrt(512): 1-term, ring-3 counted vmcnt
    gemm3<4,1,1><<<dim3(16, 16, 4), 256, 0, stream>>>(qh, nullptr, kh, nullptr, nullptr,
        nullptr, sh, nullptr, 512, 512, 512, 2048,
        (long)SEQ * 512, (long)SEQ * 512, (long)SEQ * SEQ,
        0.044194173824159216f, 1);

    // 4. softmax rows (bf16 in/out)
    softmax_kernel<<<ROWS, 256, 0, stream>>>(sh);

    // 5. att = p @ v: 1-term, ring-3; split output (feeds 3-term final)
    gemm3<2,1,1><<<dim3(16, 8, 4), 256, 0, stream>>>(sh, nullptr, vTh, nullptr, nullptr,
        nullptr, ath, atl, 2048, 2048, 2048, 512,
        (long)SEQ * SEQ, (long)512 * SEQ, (long)SEQ * 512,
        1.0f, 1);

    // 6. out = att @ Wo^T + bo: 3-term, 2-buffer, fp32 out
    gemm2<2,2,2><<<dim3(64, 8, 1), 256, 0, stream>>>(ath, atl, woh, wol, bo,
        (float*)d_out, nullptr, nullptr, 512, 512, 512, 512,
        0, 0, 0, 1.0f, 0);
}